// Round 11
// baseline (169.054 us; speedup 1.0000x reference)
//
#include <hip/hip_runtime.h>

#define M_HYP 20
#define AS1 __attribute__((address_space(1)))
#define AS3 __attribute__((address_space(3)))

// ======================================================================
// EXACT numpy fp32 pairwise summation.
// Invariant: N=100000 => every split point (n/2)&~7 keeps child sizes and
// offsets multiples of 8, so every leaf has n%8==0 and the 8-accumulator
// leaf loop maps 1:1 onto float4 pairs with the exact same operand order
// as numpy's scalar code. LDS staging (512-elem tiles) is pure data
// movement: the arithmetic sequence is bit-identical to round 8.
// ======================================================================

__device__ __forceinline__ float comb8(const float r[8]) {
    return __fadd_rn(__fadd_rn(__fadd_rn(r[0], r[1]), __fadd_rn(r[2], r[3])),
                     __fadd_rn(__fadd_rn(r[4], r[5]), __fadd_rn(r[6], r[7])));
}

// ---------------- raw (cog) path: plain global loads ----------------
struct RawF { const float* a; };

__device__ __forceinline__ void raw8(const RawF& f, int k, float e[8]) {
    float4 v0 = *(const float4*)(f.a + k);
    float4 v1 = *(const float4*)(f.a + k + 4);
    e[0] = v0.x; e[1] = v0.y; e[2] = v0.z; e[3] = v0.w;
    e[4] = v1.x; e[5] = v1.y; e[6] = v1.z; e[7] = v1.w;
}

__device__ float leaf_raw(const RawF& f, int off, int n) {
    float r[8], e[8];
    raw8(f, off, e);
#pragma unroll
    for (int j = 0; j < 8; ++j) r[j] = e[j];
    for (int i = 8; i < n; i += 8) {
        raw8(f, off + i, e);
#pragma unroll
        for (int j = 0; j < 8; ++j) r[j] = __fadd_rn(r[j], e[j]);
    }
    return comb8(r);
}

__device__ float tree_raw(const RawF& f, int off0, int n0) {
    float lsum[14]; int roff[14], rn[14]; unsigned have = 0;
    int sp = 0, off = off0, n = n0;
    while (true) {
        while (n > 128) {
            int n2 = (n / 2) & ~7;
            roff[sp] = off + n2; rn[sp] = n - n2;
            have &= ~(1u << sp); ++sp;
            n = n2;
        }
        float s = leaf_raw(f, off, n);
        while (sp > 0 && (have & (1u << (sp - 1)))) {
            --sp; s = __fadd_rn(lsum[sp], s);
        }
        if (sp == 0) return s;
        lsum[sp - 1] = s; have |= (1u << (sp - 1));
        off = roff[sp - 1]; n = rn[sp - 1];
    }
}

// ---------------- err path: LDS-staged streams, 512-elem tiles ----------------
// 6 streams staged in 512-element tiles; row stride 520 (mod-32-banks = 8)
// keeps the q rows on distinct banks (same pattern as the 264 pad: 0 conflicts).
struct Stg {
    const float *g0, *g1, *g2, *g3, *g4, *g5;   // global stream bases
    float (*sm)[520];                            // [6][520] LDS
    int tile_base;                               // staged tile start (element idx)
    int node_end;                                // node end (element idx)
    int lane;
    int qs;                                      // 3 + c (per-lane q row)
    float t0, t1, t2, t3;
};

__device__ __forceinline__ void stage6(Stg& st, int t) {
    int rel = st.lane * 4;
    // clamp lanes whose 4-float granule would cross node_end (their LDS
    // slots are never read); granules never partially cross (8|sizes).
    int srcA = (rel + 4 <= st.node_end - t) ? (t + rel) : t;
    int srcB = (rel + 260 <= st.node_end - t) ? (t + 256 + rel) : t;
    __builtin_amdgcn_global_load_lds((const AS1 float*)(st.g0 + srcA), (AS3 float*)&st.sm[0][0],   16, 0, 0);
    __builtin_amdgcn_global_load_lds((const AS1 float*)(st.g1 + srcA), (AS3 float*)&st.sm[1][0],   16, 0, 0);
    __builtin_amdgcn_global_load_lds((const AS1 float*)(st.g2 + srcA), (AS3 float*)&st.sm[2][0],   16, 0, 0);
    __builtin_amdgcn_global_load_lds((const AS1 float*)(st.g3 + srcA), (AS3 float*)&st.sm[3][0],   16, 0, 0);
    __builtin_amdgcn_global_load_lds((const AS1 float*)(st.g4 + srcA), (AS3 float*)&st.sm[4][0],   16, 0, 0);
    __builtin_amdgcn_global_load_lds((const AS1 float*)(st.g5 + srcA), (AS3 float*)&st.sm[5][0],   16, 0, 0);
    __builtin_amdgcn_global_load_lds((const AS1 float*)(st.g0 + srcB), (AS3 float*)&st.sm[0][256], 16, 0, 0);
    __builtin_amdgcn_global_load_lds((const AS1 float*)(st.g1 + srcB), (AS3 float*)&st.sm[1][256], 16, 0, 0);
    __builtin_amdgcn_global_load_lds((const AS1 float*)(st.g2 + srcB), (AS3 float*)&st.sm[2][256], 16, 0, 0);
    __builtin_amdgcn_global_load_lds((const AS1 float*)(st.g3 + srcB), (AS3 float*)&st.sm[3][256], 16, 0, 0);
    __builtin_amdgcn_global_load_lds((const AS1 float*)(st.g4 + srcB), (AS3 float*)&st.sm[4][256], 16, 0, 0);
    __builtin_amdgcn_global_load_lds((const AS1 float*)(st.g5 + srcB), (AS3 float*)&st.sm[5][256], 16, 0, 0);
    asm volatile("s_waitcnt vmcnt(0)" ::: "memory");
    __builtin_amdgcn_sched_barrier(0);
}

__device__ __forceinline__ void chunk8(Stg& st, int g, float e[8]) {
    if (g - st.tile_base >= 512) {       // wave-uniform branch; sequential g
        st.tile_base = g;
        stage6(st, g);
    }
    int k = g - st.tile_base;            // 8-aligned -> 32B-aligned LDS reads
    float4 a0 = *(const float4*)&st.sm[0][k];
    float4 a1 = *(const float4*)&st.sm[0][k + 4];
    float4 b0 = *(const float4*)&st.sm[1][k];
    float4 b1 = *(const float4*)&st.sm[1][k + 4];
    float4 c0 = *(const float4*)&st.sm[2][k];
    float4 c1 = *(const float4*)&st.sm[2][k + 4];
    const float* qr = &st.sm[st.qs][0];
    float4 d0 = *(const float4*)&qr[k];
    float4 d1 = *(const float4*)&qr[k + 4];
    float px[8] = {a0.x, a0.y, a0.z, a0.w, a1.x, a1.y, a1.z, a1.w};
    float py[8] = {b0.x, b0.y, b0.z, b0.w, b1.x, b1.y, b1.z, b1.w};
    float pz[8] = {c0.x, c0.y, c0.z, c0.w, c1.x, c1.y, c1.z, c1.w};
    float qq[8] = {d0.x, d0.y, d0.z, d0.w, d1.x, d1.y, d1.z, d1.w};
#pragma unroll
    for (int j = 0; j < 8; ++j) {
        float s = __fmul_rn(st.t0, px[j]);   // exact op order of the einsum
        s = fmaf(st.t1, py[j], s);
        s = fmaf(st.t2, pz[j], s);
        s = __fadd_rn(s, st.t3);
        float d = __fsub_rn(s, qq[j]);
        e[j] = __fmul_rn(d, d);
    }
}

__device__ float leaf_err(Stg& st, int off, int n) {
    float r[8], e[8];
    chunk8(st, off, e);
#pragma unroll
    for (int j = 0; j < 8; ++j) r[j] = e[j];
    for (int i = 8; i < n; i += 8) {
        chunk8(st, off + i, e);
#pragma unroll
        for (int j = 0; j < 8; ++j) r[j] = __fadd_rn(r[j], e[j]);
    }
    return comb8(r);
}

__device__ float tree_err(Stg& st, int off0, int n0) {
    float lsum[14]; int roff[14], rn[14]; unsigned have = 0;
    int sp = 0, off = off0, n = n0;
    while (true) {
        while (n > 128) {
            int n2 = (n / 2) & ~7;
            roff[sp] = off + n2; rn[sp] = n - n2;
            have &= ~(1u << sp); ++sp;
            n = n2;
        }
        float s = leaf_err(st, off, n);
        while (sp > 0 && (have & (1u << (sp - 1)))) {
            --sp; s = __fadd_rn(lsum[sp], s);
        }
        if (sp == 0) return s;
        lsum[sp - 1] = s; have |= (1u << (sp - 1));
        off = roff[sp - 1]; n = rn[sp - 1];
    }
}

// ================= fp32 LAPACK (netlib / OpenBLAS) emulation =================
#define F32EPS  5.9604645e-8f
#define F32UNFL 1.17549435e-38f

__device__ inline float f32_slapy2(float x, float y) {
    float xa = fabsf(x), ya = fabsf(y);
    float w = fmaxf(xa, ya), z = fminf(xa, ya);
    if (z == 0.0f) return w;
    float t = __fdiv_rn(z, w);
    return __fmul_rn(w, __fsqrt_rn(fmaf(t, t, 1.0f)));
}

__device__ inline float snrm2_2(float x0, float x1) {
    double s = (double)x0 * (double)x0 + (double)x1 * (double)x1;
    return (float)sqrt(s);
}

__device__ inline float f32_slarfg(int nx, float& alpha, float* x) {
    if (nx <= 0) return 0.0f;
    float xnorm = (nx == 1) ? fabsf(x[0]) : snrm2_2(x[0], x[1]);
    if (xnorm == 0.0f) return 0.0f;
    float beta = -copysignf(f32_slapy2(alpha, xnorm), alpha);
    float tau = __fdiv_rn(__fsub_rn(beta, alpha), beta);
    float sc = __fdiv_rn(1.0f, __fsub_rn(alpha, beta));
    for (int i = 0; i < nx; ++i) x[i] = __fmul_rn(x[i], sc);
    alpha = beta;
    return tau;
}

__device__ inline void f32_slartg(float f, float g, float& c, float& s, float& r) {
    float f1 = fabsf(f), g1 = fabsf(g);
    if (g == 0.0f) { c = 1.0f; s = 0.0f; r = f; }
    else if (f == 0.0f) { c = 0.0f; s = copysignf(1.0f, g); r = g1; }
    else {
        float d = __fsqrt_rn(fmaf(f, f, __fmul_rn(g, g)));
        float p = __fdiv_rn(1.0f, d);
        c = __fmul_rn(f1, p);
        s = __fmul_rn(g, copysignf(p, f));
        r = copysignf(d, f);
    }
}

__device__ inline void f32_slas2(float f, float g, float h, float& ssmin, float& ssmax) {
    float fa = fabsf(f), ga = fabsf(g), ha = fabsf(h);
    float fhmn = fminf(fa, ha), fhmx = fmaxf(fa, ha);
    if (fhmn == 0.0f) {
        ssmin = 0.0f;
        if (fhmx == 0.0f) ssmax = ga;
        else {
            float mx = fmaxf(fhmx, ga), mn = fminf(fhmx, ga);
            float t = __fdiv_rn(mn, mx);
            ssmax = __fmul_rn(mx, __fsqrt_rn(fmaf(t, t, 1.0f)));
        }
    } else {
        if (ga < fhmx) {
            float as = __fadd_rn(1.0f, __fdiv_rn(fhmn, fhmx));
            float at = __fdiv_rn(__fsub_rn(fhmx, fhmn), fhmx);
            float q = __fdiv_rn(ga, fhmx);
            float au = __fmul_rn(q, q);
            float c = __fdiv_rn(2.0f, __fadd_rn(__fsqrt_rn(fmaf(as, as, au)),
                                                __fsqrt_rn(fmaf(at, at, au))));
            ssmin = __fmul_rn(fhmn, c);
            ssmax = __fdiv_rn(fhmx, c);
        } else {
            float au = __fdiv_rn(fhmx, ga);
            if (au == 0.0f) {
                ssmin = __fdiv_rn(__fmul_rn(fhmn, fhmx), ga);
                ssmax = ga;
            } else {
                float as = __fadd_rn(1.0f, __fdiv_rn(fhmn, fhmx));
                float at = __fdiv_rn(__fsub_rn(fhmx, fhmn), fhmx);
                float u1 = __fmul_rn(as, au), u2 = __fmul_rn(at, au);
                float c = __fdiv_rn(1.0f, __fadd_rn(__fsqrt_rn(fmaf(u1, u1, 1.0f)),
                                                    __fsqrt_rn(fmaf(u2, u2, 1.0f))));
                ssmin = __fmul_rn(__fmul_rn(fhmn, c), au);
                ssmin = __fadd_rn(ssmin, ssmin);
                ssmax = __fdiv_rn(ga, __fadd_rn(c, c));
            }
        }
    }
}

__device__ inline void f32_slasv2(float f, float g, float h,
                                  float& ssmin, float& ssmax,
                                  float& snr, float& csr, float& snl, float& csl) {
    float ft = f, fa = fabsf(f), ht = h, ha = fabsf(h);
    int pmax = 1;
    bool swp = (ha > fa);
    if (swp) { pmax = 3; float t = ft; ft = ht; ht = t; t = fa; fa = ha; ha = t; }
    float gt = g, ga = fabsf(gt);
    float clt = 0.f, crt = 0.f, slt = 0.f, srt = 0.f;
    if (ga == 0.0f) {
        ssmin = ha; ssmax = fa; clt = 1.0f; crt = 1.0f; slt = 0.0f; srt = 0.0f;
    } else {
        bool gasmal = true;
        if (ga > fa) {
            pmax = 2;
            if (__fdiv_rn(fa, ga) < F32EPS) {
                gasmal = false;
                ssmax = ga;
                if (ha > 1.0f) ssmin = __fdiv_rn(fa, __fdiv_rn(ga, ha));
                else           ssmin = __fmul_rn(__fdiv_rn(fa, ga), ha);
                clt = 1.0f; slt = __fdiv_rn(ht, gt);
                srt = 1.0f; crt = __fdiv_rn(ft, gt);
            }
        }
        if (gasmal) {
            float dd = __fsub_rn(fa, ha);
            float l = (dd == fa) ? 1.0f : __fdiv_rn(dd, fa);
            float vm = __fdiv_rn(gt, ft);
            float t = __fsub_rn(2.0f, l);
            float mm = __fmul_rn(vm, vm);
            float s = __fsqrt_rn(fmaf(t, t, mm));
            float r = (l == 0.0f) ? fabsf(vm) : __fsqrt_rn(fmaf(l, l, mm));
            float a = __fmul_rn(0.5f, __fadd_rn(s, r));
            ssmin = __fdiv_rn(ha, a);
            ssmax = __fmul_rn(fa, a);
            if (mm == 0.0f) {
                if (l == 0.0f) t = __fmul_rn(copysignf(2.0f, ft), copysignf(1.0f, gt));
                else t = __fadd_rn(__fdiv_rn(gt, copysignf(dd, ft)), __fdiv_rn(vm, t));
            } else {
                t = __fmul_rn(__fadd_rn(__fdiv_rn(vm, __fadd_rn(s, t)),
                                        __fdiv_rn(vm, __fadd_rn(r, l))),
                              __fadd_rn(1.0f, a));
            }
            float l2 = __fsqrt_rn(fmaf(t, t, 4.0f));
            crt = __fdiv_rn(2.0f, l2);
            srt = __fdiv_rn(t, l2);
            clt = __fdiv_rn(fmaf(srt, vm, crt), a);
            slt = __fdiv_rn(__fmul_rn(__fdiv_rn(ht, ft), srt), a);
        }
    }
    if (swp) { csl = srt; snl = crt; csr = slt; snr = clt; }
    else     { csl = clt; snl = slt; csr = crt; snr = srt; }
    float tsign = 0.f;
    if (pmax == 1) tsign = __fmul_rn(__fmul_rn(copysignf(1.0f, csr), copysignf(1.0f, csl)), copysignf(1.0f, f));
    if (pmax == 2) tsign = __fmul_rn(__fmul_rn(copysignf(1.0f, snr), copysignf(1.0f, csl)), copysignf(1.0f, g));
    if (pmax == 3) tsign = __fmul_rn(__fmul_rn(copysignf(1.0f, snr), copysignf(1.0f, snl)), copysignf(1.0f, h));
    ssmax = copysignf(ssmax, tsign);
    ssmin = copysignf(ssmin, __fmul_rn(__fmul_rn(tsign, copysignf(1.0f, f)), copysignf(1.0f, h)));
}

__device__ inline void slasr_L(float vt[3][3], int base, int len, const float* c, const float* s, bool fwd) {
    int pairs = len - 1;
    for (int jj = 0; jj < pairs; ++jj) {
        int j = fwd ? jj : (pairs - 1 - jj);
        float cj = c[j], sj = s[j];
        if (cj != 1.0f || sj != 0.0f) {
            for (int i = 0; i < 3; ++i) {
                float temp = vt[base + j + 1][i];
                vt[base + j + 1][i] = fmaf(cj, temp, -__fmul_rn(sj, vt[base + j][i]));
                vt[base + j][i]     = fmaf(sj, temp,  __fmul_rn(cj, vt[base + j][i]));
            }
        }
    }
}
__device__ inline void slasr_R(float u[3][3], int base, int len, const float* c, const float* s, bool fwd) {
    int pairs = len - 1;
    for (int jj = 0; jj < pairs; ++jj) {
        int j = fwd ? jj : (pairs - 1 - jj);
        float cj = c[j], sj = s[j];
        if (cj != 1.0f || sj != 0.0f) {
            for (int i = 0; i < 3; ++i) {
                float temp = u[i][base + j + 1];
                u[i][base + j + 1] = fmaf(cj, temp, -__fmul_rn(sj, u[i][base + j]));
                u[i][base + j]     = fmaf(sj, temp,  __fmul_rn(cj, u[i][base + j]));
            }
        }
    }
}

__device__ void f32_sbdsqr3(float d[3], float e[2], float vt[3][3], float u[3][3]) {
    const int N = 3;
    float TOL = __fmul_rn(10.0f, F32EPS);
    float thresh;
    {
        float sminoa = fabsf(d[0]);
        if (sminoa != 0.0f) {
            float mu = sminoa;
            for (int i = 1; i < N; ++i) {
                mu = __fmul_rn(fabsf(d[i]), __fdiv_rn(mu, __fadd_rn(mu, fabsf(e[i - 1]))));
                sminoa = fminf(sminoa, mu);
                if (sminoa == 0.0f) break;
            }
        }
        sminoa = __fdiv_rn(sminoa, __fsqrt_rn((float)N));
        thresh = fmaxf(__fmul_rn(TOL, sminoa), __fmul_rn(54.0f, F32UNFL));
    }
    int m = N, oldll = -1, oldm = -1, idir = 0;
    int guard = 0;
    while (true) {
        if (m <= 1) break;
        if (++guard > 400) break;
        int ll = 0;
        float smax_blk = fabsf(d[m - 1]);
        bool split = false;
        for (int lll = 1; lll <= m - 1; ++lll) {
            ll = m - lll;
            float abss = fabsf(d[ll - 1]);
            float abse = fabsf(e[ll - 1]);
            if (abse <= thresh) { split = true; break; }
            smax_blk = fmaxf(smax_blk, fmaxf(abss, abse));
        }
        if (split) {
            e[ll - 1] = 0.0f;
            if (ll == m - 1) { m -= 1; continue; }
            ll += 1;
        } else ll = 1;
        if (ll == m - 1) {
            float sigmn, sigmx, sinr, cosr, sinl, cosl;
            f32_slasv2(d[m - 2], e[m - 2], d[m - 1], sigmn, sigmx, sinr, cosr, sinl, cosl);
            d[m - 2] = sigmx; e[m - 2] = 0.0f; d[m - 1] = sigmn;
            for (int i = 0; i < 3; ++i) {
                float x = vt[m - 2][i], y = vt[m - 1][i];
                float temp = fmaf(cosr, x, __fmul_rn(sinr, y));
                vt[m - 1][i] = fmaf(cosr, y, -__fmul_rn(sinr, x));
                vt[m - 2][i] = temp;
            }
            for (int i = 0; i < 3; ++i) {
                float x = u[i][m - 2], y = u[i][m - 1];
                float temp = fmaf(cosl, x, __fmul_rn(sinl, y));
                u[i][m - 1] = fmaf(cosl, y, -__fmul_rn(sinl, x));
                u[i][m - 2] = temp;
            }
            m -= 2;
            continue;
        }
        if (ll > oldm || m < oldll)
            idir = (fabsf(d[ll - 1]) >= fabsf(d[m - 1])) ? 1 : 2;
        float sminl = 0.0f;
        bool deflated = false;
        if (idir == 1) {
            if (fabsf(e[m - 2]) <= __fmul_rn(fabsf(TOL), fabsf(d[m - 1]))) { e[m - 2] = 0.0f; continue; }
            float mu = fabsf(d[ll - 1]);
            sminl = mu;
            for (int lll = ll; lll <= m - 1; ++lll) {
                if (fabsf(e[lll - 1]) <= __fmul_rn(TOL, mu)) { e[lll - 1] = 0.0f; deflated = true; break; }
                mu = __fmul_rn(fabsf(d[lll]), __fdiv_rn(mu, __fadd_rn(mu, fabsf(e[lll - 1]))));
                sminl = fminf(sminl, mu);
            }
        } else {
            if (fabsf(e[ll - 1]) <= __fmul_rn(fabsf(TOL), fabsf(d[ll - 1]))) { e[ll - 1] = 0.0f; continue; }
            float mu = fabsf(d[m - 1]);
            sminl = mu;
            for (int lll = m - 1; lll >= ll; --lll) {
                if (fabsf(e[lll - 1]) <= __fmul_rn(TOL, mu)) { e[lll - 1] = 0.0f; deflated = true; break; }
                mu = __fmul_rn(fabsf(d[lll - 1]), __fdiv_rn(mu, __fadd_rn(mu, fabsf(e[lll - 1]))));
                sminl = fminf(sminl, mu);
            }
        }
        if (deflated) continue;
        oldll = ll; oldm = m;
        float shift = 0.0f, rdum;
        {
            float lhs = __fmul_rn(__fmul_rn((float)N, TOL), __fdiv_rn(sminl, smax_blk));
            float rhs = fmaxf(F32EPS, __fmul_rn(0.01f, TOL));
            if (lhs <= rhs) shift = 0.0f;
            else {
                float sll;
                if (idir == 1) { sll = fabsf(d[ll - 1]); f32_slas2(d[m - 2], e[m - 2], d[m - 1], shift, rdum); }
                else           { sll = fabsf(d[m - 1]);  f32_slas2(d[ll - 1], e[ll - 1], d[ll], shift, rdum); }
                if (sll > 0.0f) {
                    float q = __fdiv_rn(shift, sll);
                    if (__fmul_rn(q, q) < F32EPS) shift = 0.0f;
                }
            }
        }
        float wcs[2], wsn[2], wocs[2], wosn[2];
        int len = m - ll + 1;
        if (shift == 0.0f) {
            if (idir == 1) {
                float cs = 1.0f, oldcs = 1.0f, sn, oldsn = 0.0f, r;
                for (int i = ll; i <= m - 1; ++i) {
                    float fin = __fmul_rn(d[i - 1], cs);
                    f32_slartg(fin, e[i - 1], cs, sn, r);
                    if (i > ll) e[i - 2] = __fmul_rn(oldsn, r);
                    float g = __fmul_rn(d[i], sn);
                    f32_slartg(__fmul_rn(oldcs, r), g, oldcs, oldsn, d[i - 1]);
                    wcs[i - ll] = cs; wsn[i - ll] = sn; wocs[i - ll] = oldcs; wosn[i - ll] = oldsn;
                }
                float h = __fmul_rn(d[m - 1], cs);
                d[m - 1] = __fmul_rn(h, oldcs);
                e[m - 2] = __fmul_rn(h, oldsn);
                slasr_L(vt, ll - 1, len, wcs, wsn, true);
                slasr_R(u, ll - 1, len, wocs, wosn, true);
                if (fabsf(e[m - 2]) <= thresh) e[m - 2] = 0.0f;
            } else {
                float cs = 1.0f, oldcs = 1.0f, sn, oldsn = 0.0f, r;
                for (int i = m; i >= ll + 1; --i) {
                    float fin = __fmul_rn(d[i - 1], cs);
                    f32_slartg(fin, e[i - 2], cs, sn, r);
                    if (i < m) e[i - 1] = __fmul_rn(oldsn, r);
                    float g = __fmul_rn(d[i - 2], sn);
                    f32_slartg(__fmul_rn(oldcs, r), g, oldcs, oldsn, d[i - 1]);
                    wcs[i - ll - 1] = cs; wsn[i - ll - 1] = -sn;
                    wocs[i - ll - 1] = oldcs; wosn[i - ll - 1] = -oldsn;
                }
                float h = __fmul_rn(d[ll - 1], cs);
                d[ll - 1] = __fmul_rn(h, oldcs);
                e[ll - 1] = __fmul_rn(h, oldsn);
                slasr_L(vt, ll - 1, len, wocs, wosn, false);
                slasr_R(u, ll - 1, len, wcs, wsn, false);
                if (fabsf(e[ll - 1]) <= thresh) e[ll - 1] = 0.0f;
            }
        } else {
            if (idir == 1) {
                float f = __fmul_rn(__fsub_rn(fabsf(d[ll - 1]), shift),
                                    __fadd_rn(copysignf(1.0f, d[ll - 1]), __fdiv_rn(shift, d[ll - 1])));
                float g = e[ll - 1];
                float cosr, sinr, cosl, sinl, r;
                for (int i = ll; i <= m - 1; ++i) {
                    f32_slartg(f, g, cosr, sinr, r);
                    if (i > ll) e[i - 2] = r;
                    f        = fmaf(cosr, d[i - 1],  __fmul_rn(sinr, e[i - 1]));
                    e[i - 1] = fmaf(cosr, e[i - 1], -__fmul_rn(sinr, d[i - 1]));
                    g = __fmul_rn(sinr, d[i]);
                    d[i] = __fmul_rn(cosr, d[i]);
                    f32_slartg(f, g, cosl, sinl, r);
                    d[i - 1] = r;
                    f    = fmaf(cosl, e[i - 1],  __fmul_rn(sinl, d[i]));
                    d[i] = fmaf(cosl, d[i],     -__fmul_rn(sinl, e[i - 1]));
                    if (i < m - 1) {
                        g = __fmul_rn(sinl, e[i]);
                        e[i] = __fmul_rn(cosl, e[i]);
                    }
                    wcs[i - ll] = cosr; wsn[i - ll] = sinr; wocs[i - ll] = cosl; wosn[i - ll] = sinl;
                }
                e[m - 2] = f;
                if (fabsf(e[m - 2]) <= thresh) e[m - 2] = 0.0f;
                slasr_L(vt, ll - 1, len, wcs, wsn, true);
                slasr_R(u, ll - 1, len, wocs, wosn, true);
            } else {
                float f = __fmul_rn(__fsub_rn(fabsf(d[m - 1]), shift),
                                    __fadd_rn(copysignf(1.0f, d[m - 1]), __fdiv_rn(shift, d[m - 1])));
                float g = e[m - 2];
                float cosr, sinr, cosl, sinl, r;
                for (int i = m; i >= ll + 1; --i) {
                    f32_slartg(f, g, cosr, sinr, r);
                    if (i < m) e[i - 1] = r;
                    f        = fmaf(cosr, d[i - 1],  __fmul_rn(sinr, e[i - 2]));
                    e[i - 2] = fmaf(cosr, e[i - 2], -__fmul_rn(sinr, d[i - 1]));
                    g = __fmul_rn(sinr, d[i - 2]);
                    d[i - 2] = __fmul_rn(cosr, d[i - 2]);
                    f32_slartg(f, g, cosl, sinl, r);
                    d[i - 1] = r;
                    f        = fmaf(cosl, e[i - 2],  __fmul_rn(sinl, d[i - 2]));
                    d[i - 2] = fmaf(cosl, d[i - 2], -__fmul_rn(sinl, e[i - 2]));
                    if (i > ll + 1) {
                        g = __fmul_rn(sinl, e[i - 3]);
                        e[i - 3] = __fmul_rn(cosl, e[i - 3]);
                    }
                    wcs[i - ll - 1] = cosr; wsn[i - ll - 1] = -sinr;
                    wocs[i - ll - 1] = cosl; wosn[i - ll - 1] = -sinl;
                }
                e[ll - 1] = f;
                if (fabsf(e[ll - 1]) <= thresh) e[ll - 1] = 0.0f;
                slasr_L(vt, ll - 1, len, wocs, wosn, false);
                slasr_R(u, ll - 1, len, wcs, wsn, false);
            }
        }
    }
    for (int i = 0; i < N; ++i) {
        if (d[i] < 0.0f) {
            d[i] = -d[i];
            for (int j = 0; j < 3; ++j) vt[i][j] = __fmul_rn(-1.0f, vt[i][j]);
        }
    }
    for (int i = 1; i <= N - 1; ++i) {
        int isub = 0; float smin = d[0];
        for (int j = 1; j <= N - i; ++j)
            if (d[j] <= smin) { isub = j; smin = d[j]; }
        int tgt = N - i;
        if (isub != tgt) {
            d[isub] = d[tgt]; d[tgt] = smin;
            for (int j = 0; j < 3; ++j) { float t = vt[isub][j]; vt[isub][j] = vt[tgt][j]; vt[tgt][j] = t; }
            for (int j = 0; j < 3; ++j) { float t = u[j][isub]; u[j][isub] = u[j][tgt]; u[j][tgt] = t; }
        }
    }
}

__device__ void sgesdd3_rot(float a[3][3], float rot[3][3]) {
    float d[3], e[2], tauq2, tauq1, taup1;
    {
        float x[2] = { a[1][0], a[2][0] };
        float alpha = a[0][0];
        tauq1 = f32_slarfg(2, alpha, x);
        a[1][0] = x[0]; a[2][0] = x[1];
        d[0] = alpha;
        if (tauq1 != 0.0f) {
            float v1 = a[1][0], v2 = a[2][0];
            for (int j = 1; j < 3; ++j) {
                float w = a[0][j];
                w = fmaf(a[1][j], v1, w);
                w = fmaf(a[2][j], v2, w);
                float tmp = __fmul_rn(-tauq1, w);
                a[0][j] = __fadd_rn(a[0][j], tmp);
                a[1][j] = fmaf(v1, tmp, a[1][j]);
                a[2][j] = fmaf(v2, tmp, a[2][j]);
            }
        }
    }
    {
        float x[1] = { a[0][2] };
        float alpha = a[0][1];
        taup1 = f32_slarfg(1, alpha, x);
        a[0][2] = x[0];
        e[0] = alpha; a[0][1] = alpha;
        if (taup1 != 0.0f) {
            float v1 = a[0][2];
            float w1 = fmaf(a[1][2], v1, a[1][1]);
            float w2 = fmaf(a[2][2], v1, a[2][1]);
            float nt = -taup1;
            float t0 = __fmul_rn(nt, 1.0f);
            a[1][1] = fmaf(w1, t0, a[1][1]);
            a[2][1] = fmaf(w2, t0, a[2][1]);
            float t1 = __fmul_rn(nt, v1);
            a[1][2] = fmaf(w1, t1, a[1][2]);
            a[2][2] = fmaf(w2, t1, a[2][2]);
        }
    }
    {
        float x[1] = { a[2][1] };
        float alpha = a[1][1];
        tauq2 = f32_slarfg(1, alpha, x);
        a[2][1] = x[0];
        d[1] = alpha;
        if (tauq2 != 0.0f) {
            float v1 = a[2][1];
            float w = a[1][2];
            w = fmaf(a[2][2], v1, w);
            float tmp = __fmul_rn(-tauq2, w);
            a[1][2] = __fadd_rn(a[1][2], tmp);
            a[2][2] = fmaf(v1, tmp, a[2][2]);
        }
        e[1] = a[1][2];
    }
    d[2] = a[2][2];
    float u[3][3], vt[3][3];
    for (int i = 0; i < 3; ++i)
        for (int j = 0; j < 3; ++j) { u[i][j] = (i == j) ? 1.0f : 0.0f; vt[i][j] = (i == j) ? 1.0f : 0.0f; }
    f32_sbdsqr3(d, e, vt, u);
    if (tauq2 != 0.0f) {
        float v1 = a[2][1];
        for (int j = 0; j < 3; ++j) {
            float w = u[1][j];
            w = fmaf(u[2][j], v1, w);
            float tmp = __fmul_rn(-tauq2, w);
            u[1][j] = __fadd_rn(u[1][j], tmp);
            u[2][j] = fmaf(v1, tmp, u[2][j]);
        }
    }
    if (tauq1 != 0.0f) {
        float v1 = a[1][0], v2 = a[2][0];
        for (int j = 0; j < 3; ++j) {
            float w = u[0][j];
            w = fmaf(u[1][j], v1, w);
            w = fmaf(u[2][j], v2, w);
            float tmp = __fmul_rn(-tauq1, w);
            u[0][j] = __fadd_rn(u[0][j], tmp);
            u[1][j] = fmaf(v1, tmp, u[1][j]);
            u[2][j] = fmaf(v2, tmp, u[2][j]);
        }
    }
    if (taup1 != 0.0f) {
        float v1 = a[0][2];
        float w0 = fmaf(vt[0][2], v1, vt[0][1]);
        float w1 = fmaf(vt[1][2], v1, vt[1][1]);
        float w2 = fmaf(vt[2][2], v1, vt[2][1]);
        float nt = -taup1;
        float t0 = __fmul_rn(nt, 1.0f);
        vt[0][1] = fmaf(w0, t0, vt[0][1]);
        vt[1][1] = fmaf(w1, t0, vt[1][1]);
        vt[2][1] = fmaf(w2, t0, vt[2][1]);
        float t1 = __fmul_rn(nt, v1);
        vt[0][2] = fmaf(w0, t1, vt[0][2]);
        vt[1][2] = fmaf(w1, t1, vt[1][2]);
        vt[2][2] = fmaf(w2, t1, vt[2][2]);
    }
    for (int i = 0; i < 3; ++i)
        for (int j = 0; j < 3; ++j) {
            float acc = __fmul_rn(vt[0][i], u[j][0]);
            acc = __fadd_rn(acc, __fmul_rn(vt[1][i], u[j][1]));
            acc = __fadd_rn(acc, __fmul_rn(vt[2][i], u[j][2]));
            rot[i][j] = acc;
        }
}

// ================= kernels =================

// grid = inst*4 (quarter blocks); block 384 = 6 waves (wave=channel).
__global__ __launch_bounds__(384)
void cog_kernel(const float* __restrict__ A, const float* __restrict__ Ag,
                const float* __restrict__ Bc, const float* __restrict__ Bg,
                int Bn, long long N, float* __restrict__ cogs /*[inst][6][4]*/)
{
    int inst = blockIdx.x >> 2;
    int qt = blockIdx.x & 3;
    int pair = inst / Bn, b = inst % Bn;
    const float* P = (pair ? Bc : A)  + (long long)b * 3 * N;
    const float* Q = (pair ? Bg : Ag) + (long long)b * 3 * N;
    int ch = threadIdx.x >> 6, lane = threadIdx.x & 63;
    RawF f;
    f.a = (ch < 3) ? (P + (long long)ch * N) : (Q + (long long)(ch - 3) * N);
    int node = qt * 64 + lane;
    int off = 0, n = (int)N;
#pragma unroll
    for (int lvl = 7; lvl >= 0; --lvl) {
        int n2 = (n / 2) & ~7;
        if ((node >> lvl) & 1) { off += n2; n -= n2; } else n = n2;
    }
    float s = tree_raw(f, off, n);
#pragma unroll
    for (int lvl = 0; lvl < 6; ++lvl)
        s = __fadd_rn(s, __shfl_down(s, 1 << lvl, 64));
    if (lane == 0) cogs[(inst * 6 + ch) * 4 + qt] = s;
}

__global__ __launch_bounds__(64)
void hypoT_kernel(const float* __restrict__ A, const float* __restrict__ Ag,
                  const float* __restrict__ Bc, const float* __restrict__ Bg,
                  const int* __restrict__ idxA, const int* __restrict__ idxB,
                  const float* __restrict__ cogs, int Bn, long long N,
                  float* __restrict__ Tall)
{
    int inst = blockIdx.x;
    int pair = inst / Bn, b = inst % Bn;
    const float* P = (pair ? Bc : A)  + (long long)b * 3 * N;
    const float* Q = (pair ? Bg : Ag) + (long long)b * 3 * N;
    const int* idx = pair ? idxB : idxA;

    int m = threadIdx.x;
    if (m >= M_HYP) return;

    float S[6];
#pragma unroll
    for (int ch = 0; ch < 6; ++ch) {
        const float* g = cogs + (inst * 6 + ch) * 4;
        S[ch] = __fadd_rn(__fadd_rn(g[0], g[1]), __fadd_rn(g[2], g[3]));
    }

    float x[12], y[12];
#pragma unroll
    for (int j = 0; j < 12; ++j) {
        int f = m * 12 + j, c = f / 80, i = f % 80;
        int id = idx[i];
        x[j] = __fsub_rn(P[(long long)c * N + id], S[c]);
        y[j] = __fsub_rn(Q[(long long)c * N + id], S[3 + c]);
    }
    float cov[3][3];
#pragma unroll
    for (int r = 0; r < 3; ++r)
#pragma unroll
        for (int dcol = 0; dcol < 3; ++dcol) {
            float s = __fmul_rn(x[r * 4 + 0], y[dcol * 4 + 0]);
            s = __fadd_rn(s, __fmul_rn(x[r * 4 + 1], y[dcol * 4 + 1]));
            s = __fadd_rn(s, __fmul_rn(x[r * 4 + 2], y[dcol * 4 + 2]));
            s = __fadd_rn(s, __fmul_rn(x[r * 4 + 3], y[dcol * 4 + 3]));
            cov[r][dcol] = s;
        }

    float rot[3][3];
    sgesdd3_rot(cov, rot);

    float* T = Tall + ((long long)inst * M_HYP + m) * 12;
#pragma unroll
    for (int r = 0; r < 3; ++r) {
        T[r * 4 + 0] = rot[r][0];
        T[r * 4 + 1] = rot[r][1];
        T[r * 4 + 2] = rot[r][2];
        T[r * 4 + 3] = __fsub_rn(S[3 + r], S[r]);
    }
}

// grid = inst*64 (depth-6 tree nodes); block = 64 lanes = 60 (m,c) combos.
// Streams staged into LDS in 512-elem tiles via global_load_lds (width 16);
// lanes consume the identical chunk sequence from LDS (broadcast reads).
__global__ __launch_bounds__(64)
void err_partial(const float* __restrict__ A, const float* __restrict__ Ag,
                 const float* __restrict__ Bc, const float* __restrict__ Bg,
                 const float* __restrict__ Tall, int Bn, long long N,
                 float* __restrict__ partials /*[inst][20][3][64]*/)
{
    int inst = blockIdx.x >> 6;
    int node = blockIdx.x & 63;
    int pair = inst / Bn, b = inst % Bn;
    const float* P = (pair ? Bc : A)  + (long long)b * 3 * N;
    const float* Q = (pair ? Bg : Ag) + (long long)b * 3 * N;

    int lane = threadIdx.x;
    int combo = lane < 60 ? lane : 59;
    int m = combo / 3, c = combo - m * 3;
    const float* T = Tall + ((long long)inst * M_HYP + m) * 12;

    __shared__ float sm[6][520];

    int off = 0, n = (int)N;
#pragma unroll
    for (int lvl = 5; lvl >= 0; --lvl) {
        int n2 = (n / 2) & ~7;
        if ((node >> lvl) & 1) { off += n2; n -= n2; } else n = n2;
    }

    Stg st;
    st.g0 = P; st.g1 = P + N; st.g2 = P + 2 * N;
    st.g3 = Q; st.g4 = Q + N; st.g5 = Q + 2 * N;
    st.sm = sm;
    st.node_end = off + n;
    st.lane = lane;
    st.qs = 3 + c;
    st.t0 = T[c * 4 + 0]; st.t1 = T[c * 4 + 1];
    st.t2 = T[c * 4 + 2]; st.t3 = T[c * 4 + 3];
    st.tile_base = off;
    stage6(st, off);

    float s = tree_err(st, off, n);
    if (lane < 60)
        partials[(((long long)inst * M_HYP + m) * 3 + c) * 64 + node] = s;
}

// grid = Bn; combines node partials in exact tree order, sqrt, argmin,
// fp64 pivoted inverse + compose.
__global__ __launch_bounds__(64)
void final_kernel(const float* __restrict__ partials, const float* __restrict__ Tall,
                  int Bn, float* __restrict__ out)
{
    int b = blockIdx.x;
    __shared__ float errsh[2][M_HYP];
    int t = threadIdx.x;
    if (t < 2 * M_HYP) {
        int pair = t / M_HYP, m = t % M_HYP;
        int inst = pair * Bn + b;
        float S[3];
#pragma unroll
        for (int c = 0; c < 3; ++c) {
            const float* g = partials + (((long long)inst * M_HYP + m) * 3 + c) * 64;
            float v[64];
#pragma unroll
            for (int i = 0; i < 64; ++i) v[i] = g[i];
#pragma unroll
            for (int lvl = 0; lvl < 6; ++lvl) {
#pragma unroll
                for (int i = 0; i < 32; ++i)
                    if (i < (32 >> lvl)) v[i] = __fadd_rn(v[2 * i], v[2 * i + 1]);
            }
            S[c] = v[0];
        }
        errsh[pair][m] = __fsqrt_rn(__fadd_rn(__fadd_rn(S[0], S[1]), S[2]));
    }
    __syncthreads();
    if (t == 0) {
        int bm[2];
#pragma unroll
        for (int pair = 0; pair < 2; ++pair) {
            int bi = 0; float be = errsh[pair][0];
            for (int mm = 1; mm < M_HYP; ++mm)
                if (errsh[pair][mm] < be) { be = errsh[pair][mm]; bi = mm; }
            bm[pair] = bi;
        }
        float TA[16], TB[16];
        const float* TsA = Tall + ((long long)(0 * Bn + b) * M_HYP + bm[0]) * 12;
        const float* TsB = Tall + ((long long)(1 * Bn + b) * M_HYP + bm[1]) * 12;
        for (int j = 0; j < 12; ++j) { TA[j] = TsA[j]; TB[j] = TsB[j]; }
        TA[12] = TA[13] = TA[14] = 0.0f; TA[15] = 1.0f;
        TB[12] = TB[13] = TB[14] = 0.0f; TB[15] = 1.0f;

        double M[4][8];
        for (int i = 0; i < 4; ++i) {
            for (int j = 0; j < 4; ++j) { M[i][j] = (double)TA[i * 4 + j]; M[i][4 + j] = 0.0; }
            M[i][4 + i] = 1.0;
        }
        for (int cc = 0; cc < 4; ++cc) {
            int piv = cc; double mx = fabs(M[cc][cc]);
            for (int r = cc + 1; r < 4; ++r) { double v = fabs(M[r][cc]); if (v > mx) { mx = v; piv = r; } }
            if (piv != cc)
                for (int j = 0; j < 8; ++j) { double tt = M[cc][j]; M[cc][j] = M[piv][j]; M[piv][j] = tt; }
            double dd = 1.0 / M[cc][cc];
            for (int j = 0; j < 8; ++j) M[cc][j] *= dd;
            for (int r = 0; r < 4; ++r) {
                if (r == cc) continue;
                double ff = M[r][cc];
                for (int j = 0; j < 8; ++j) M[r][j] -= ff * M[cc][j];
            }
        }
        for (int i = 0; i < 4; ++i)
            for (int j = 0; j < 4; ++j) {
                double s = 0.0;
                for (int k = 0; k < 4; ++k) s += M[i][4 + k] * (double)TB[k * 4 + j];
                out[b * 16 + i * 4 + j] = (float)s;
            }
    }
}

extern "C" void kernel_launch(void* const* d_in, const int* in_sizes, int n_in,
                              void* d_out, int out_size, void* d_ws, size_t ws_size,
                              hipStream_t stream) {
    const float* A    = (const float*)d_in[0];
    const float* Ag   = (const float*)d_in[1];
    const float* Bc   = (const float*)d_in[2];
    const float* Bg   = (const float*)d_in[3];
    const int*   idxA = (const int*)d_in[4];
    const int*   idxB = (const int*)d_in[5];
    float* out = (float*)d_out;

    int Bn = out_size / 16;                              // 32
    long long N = (long long)in_sizes[0] / (3LL * Bn);   // 100000
    int inst = 2 * Bn;                                   // 64

    float* cogs     = (float*)d_ws;                              // inst*6*4
    float* Tall     = cogs + (size_t)inst * 6 * 4;               // inst*M_HYP*12
    float* partials = Tall + (size_t)inst * M_HYP * 12;          // inst*M_HYP*3*64

    cog_kernel  <<<inst * 4,  384, 0, stream>>>(A, Ag, Bc, Bg, Bn, N, cogs);
    hypoT_kernel<<<inst,       64, 0, stream>>>(A, Ag, Bc, Bg, idxA, idxB, cogs, Bn, N, Tall);
    err_partial <<<inst * 64,  64, 0, stream>>>(A, Ag, Bc, Bg, Tall, Bn, N, partials);
    final_kernel<<<Bn,         64, 0, stream>>>(partials, Tall, Bn, out);
}

// Round 12
// 148.605 us; speedup vs baseline: 1.1376x; 1.1376x over previous
//
#include <hip/hip_runtime.h>

#define M_HYP 20
#define AS1 __attribute__((address_space(1)))
#define AS3 __attribute__((address_space(3)))

// ======================================================================
// EXACT numpy fp32 pairwise summation.
// Invariant: N=100000 => every split point (n/2)&~7 keeps child sizes and
// offsets multiples of 8, so every leaf has n%8==0 and the 8-accumulator
// leaf loop maps 1:1 onto float4 pairs with the exact same operand order
// as numpy's scalar code. LDS staging (256-elem tiles, round-8 verified)
// is pure data movement; depth-7 node split preserves the exact tree
// order (final_kernel folds node pairs first — round-10 verified).
// ======================================================================

__device__ __forceinline__ float comb8(const float r[8]) {
    return __fadd_rn(__fadd_rn(__fadd_rn(r[0], r[1]), __fadd_rn(r[2], r[3])),
                     __fadd_rn(__fadd_rn(r[4], r[5]), __fadd_rn(r[6], r[7])));
}

// ---------------- raw (cog) path: plain global loads ----------------
struct RawF { const float* a; };

__device__ __forceinline__ void raw8(const RawF& f, int k, float e[8]) {
    float4 v0 = *(const float4*)(f.a + k);
    float4 v1 = *(const float4*)(f.a + k + 4);
    e[0] = v0.x; e[1] = v0.y; e[2] = v0.z; e[3] = v0.w;
    e[4] = v1.x; e[5] = v1.y; e[6] = v1.z; e[7] = v1.w;
}

__device__ float leaf_raw(const RawF& f, int off, int n) {
    float r[8], e[8];
    raw8(f, off, e);
#pragma unroll
    for (int j = 0; j < 8; ++j) r[j] = e[j];
    for (int i = 8; i < n; i += 8) {
        raw8(f, off + i, e);
#pragma unroll
        for (int j = 0; j < 8; ++j) r[j] = __fadd_rn(r[j], e[j]);
    }
    return comb8(r);
}

__device__ float tree_raw(const RawF& f, int off0, int n0) {
    float lsum[14]; int roff[14], rn[14]; unsigned have = 0;
    int sp = 0, off = off0, n = n0;
    while (true) {
        while (n > 128) {
            int n2 = (n / 2) & ~7;
            roff[sp] = off + n2; rn[sp] = n - n2;
            have &= ~(1u << sp); ++sp;
            n = n2;
        }
        float s = leaf_raw(f, off, n);
        while (sp > 0 && (have & (1u << (sp - 1)))) {
            --sp; s = __fadd_rn(lsum[sp], s);
        }
        if (sp == 0) return s;
        lsum[sp - 1] = s; have |= (1u << (sp - 1));
        off = roff[sp - 1]; n = rn[sp - 1];
    }
}

// ---------------- err path: LDS-staged streams (round-8 structure) ----------------
// 6 streams staged in 256-element tiles; row pad 264 de-aliases q-row banks.
struct Stg {
    const float *g0, *g1, *g2, *g3, *g4, *g5;   // global stream bases
    float (*sm)[264];                            // [6][264] LDS (compile-time base)
    int tile_base;                               // staged tile start (element idx)
    int node_end;                                // node end (element idx)
    int lane;
    int qs;                                      // 3 + c (per-lane q row)
    float t0, t1, t2, t3;
};

__device__ __forceinline__ void stage6(Stg& st, int t) {
    int rel = st.lane * 4;
    // clamp lanes whose 4-float granule would cross node_end (their LDS
    // slots are never read); granules never partially cross (8|sizes).
    int src = (rel + 4 <= st.node_end - t) ? (t + rel) : t;
    __builtin_amdgcn_global_load_lds((const AS1 float*)(st.g0 + src), (AS3 float*)&st.sm[0][0], 16, 0, 0);
    __builtin_amdgcn_global_load_lds((const AS1 float*)(st.g1 + src), (AS3 float*)&st.sm[1][0], 16, 0, 0);
    __builtin_amdgcn_global_load_lds((const AS1 float*)(st.g2 + src), (AS3 float*)&st.sm[2][0], 16, 0, 0);
    __builtin_amdgcn_global_load_lds((const AS1 float*)(st.g3 + src), (AS3 float*)&st.sm[3][0], 16, 0, 0);
    __builtin_amdgcn_global_load_lds((const AS1 float*)(st.g4 + src), (AS3 float*)&st.sm[4][0], 16, 0, 0);
    __builtin_amdgcn_global_load_lds((const AS1 float*)(st.g5 + src), (AS3 float*)&st.sm[5][0], 16, 0, 0);
    asm volatile("s_waitcnt vmcnt(0)" ::: "memory");
    __builtin_amdgcn_sched_barrier(0);
}

__device__ __forceinline__ void chunk8(Stg& st, int g, float e[8]) {
    if (g - st.tile_base >= 256) {       // wave-uniform branch; sequential g
        st.tile_base = g;
        stage6(st, g);
    }
    int k = g - st.tile_base;            // 8-aligned -> 32B-aligned LDS reads
    float4 a0 = *(const float4*)&st.sm[0][k];
    float4 a1 = *(const float4*)&st.sm[0][k + 4];
    float4 b0 = *(const float4*)&st.sm[1][k];
    float4 b1 = *(const float4*)&st.sm[1][k + 4];
    float4 c0 = *(const float4*)&st.sm[2][k];
    float4 c1 = *(const float4*)&st.sm[2][k + 4];
    const float* qr = &st.sm[st.qs][0];
    float4 d0 = *(const float4*)&qr[k];
    float4 d1 = *(const float4*)&qr[k + 4];
    float px[8] = {a0.x, a0.y, a0.z, a0.w, a1.x, a1.y, a1.z, a1.w};
    float py[8] = {b0.x, b0.y, b0.z, b0.w, b1.x, b1.y, b1.z, b1.w};
    float pz[8] = {c0.x, c0.y, c0.z, c0.w, c1.x, c1.y, c1.z, c1.w};
    float qq[8] = {d0.x, d0.y, d0.z, d0.w, d1.x, d1.y, d1.z, d1.w};
#pragma unroll
    for (int j = 0; j < 8; ++j) {
        float s = __fmul_rn(st.t0, px[j]);   // exact op order of the einsum
        s = fmaf(st.t1, py[j], s);
        s = fmaf(st.t2, pz[j], s);
        s = __fadd_rn(s, st.t3);
        float d = __fsub_rn(s, qq[j]);
        e[j] = __fmul_rn(d, d);
    }
}

__device__ float leaf_err(Stg& st, int off, int n) {
    float r[8], e[8];
    chunk8(st, off, e);
#pragma unroll
    for (int j = 0; j < 8; ++j) r[j] = e[j];
    for (int i = 8; i < n; i += 8) {
        chunk8(st, off + i, e);
#pragma unroll
        for (int j = 0; j < 8; ++j) r[j] = __fadd_rn(r[j], e[j]);
    }
    return comb8(r);
}

__device__ float tree_err(Stg& st, int off0, int n0) {
    float lsum[14]; int roff[14], rn[14]; unsigned have = 0;
    int sp = 0, off = off0, n = n0;
    while (true) {
        while (n > 128) {
            int n2 = (n / 2) & ~7;
            roff[sp] = off + n2; rn[sp] = n - n2;
            have &= ~(1u << sp); ++sp;
            n = n2;
        }
        float s = leaf_err(st, off, n);
        while (sp > 0 && (have & (1u << (sp - 1)))) {
            --sp; s = __fadd_rn(lsum[sp], s);
        }
        if (sp == 0) return s;
        lsum[sp - 1] = s; have |= (1u << (sp - 1));
        off = roff[sp - 1]; n = rn[sp - 1];
    }
}

// ================= fp32 LAPACK (netlib / OpenBLAS) emulation =================
#define F32EPS  5.9604645e-8f
#define F32UNFL 1.17549435e-38f

__device__ inline float f32_slapy2(float x, float y) {
    float xa = fabsf(x), ya = fabsf(y);
    float w = fmaxf(xa, ya), z = fminf(xa, ya);
    if (z == 0.0f) return w;
    float t = __fdiv_rn(z, w);
    return __fmul_rn(w, __fsqrt_rn(fmaf(t, t, 1.0f)));
}

__device__ inline float snrm2_2(float x0, float x1) {
    double s = (double)x0 * (double)x0 + (double)x1 * (double)x1;
    return (float)sqrt(s);
}

__device__ inline float f32_slarfg(int nx, float& alpha, float* x) {
    if (nx <= 0) return 0.0f;
    float xnorm = (nx == 1) ? fabsf(x[0]) : snrm2_2(x[0], x[1]);
    if (xnorm == 0.0f) return 0.0f;
    float beta = -copysignf(f32_slapy2(alpha, xnorm), alpha);
    float tau = __fdiv_rn(__fsub_rn(beta, alpha), beta);
    float sc = __fdiv_rn(1.0f, __fsub_rn(alpha, beta));
    for (int i = 0; i < nx; ++i) x[i] = __fmul_rn(x[i], sc);
    alpha = beta;
    return tau;
}

__device__ inline void f32_slartg(float f, float g, float& c, float& s, float& r) {
    float f1 = fabsf(f), g1 = fabsf(g);
    if (g == 0.0f) { c = 1.0f; s = 0.0f; r = f; }
    else if (f == 0.0f) { c = 0.0f; s = copysignf(1.0f, g); r = g1; }
    else {
        float d = __fsqrt_rn(fmaf(f, f, __fmul_rn(g, g)));
        float p = __fdiv_rn(1.0f, d);
        c = __fmul_rn(f1, p);
        s = __fmul_rn(g, copysignf(p, f));
        r = copysignf(d, f);
    }
}

__device__ inline void f32_slas2(float f, float g, float h, float& ssmin, float& ssmax) {
    float fa = fabsf(f), ga = fabsf(g), ha = fabsf(h);
    float fhmn = fminf(fa, ha), fhmx = fmaxf(fa, ha);
    if (fhmn == 0.0f) {
        ssmin = 0.0f;
        if (fhmx == 0.0f) ssmax = ga;
        else {
            float mx = fmaxf(fhmx, ga), mn = fminf(fhmx, ga);
            float t = __fdiv_rn(mn, mx);
            ssmax = __fmul_rn(mx, __fsqrt_rn(fmaf(t, t, 1.0f)));
        }
    } else {
        if (ga < fhmx) {
            float as = __fadd_rn(1.0f, __fdiv_rn(fhmn, fhmx));
            float at = __fdiv_rn(__fsub_rn(fhmx, fhmn), fhmx);
            float q = __fdiv_rn(ga, fhmx);
            float au = __fmul_rn(q, q);
            float c = __fdiv_rn(2.0f, __fadd_rn(__fsqrt_rn(fmaf(as, as, au)),
                                                __fsqrt_rn(fmaf(at, at, au))));
            ssmin = __fmul_rn(fhmn, c);
            ssmax = __fdiv_rn(fhmx, c);
        } else {
            float au = __fdiv_rn(fhmx, ga);
            if (au == 0.0f) {
                ssmin = __fdiv_rn(__fmul_rn(fhmn, fhmx), ga);
                ssmax = ga;
            } else {
                float as = __fadd_rn(1.0f, __fdiv_rn(fhmn, fhmx));
                float at = __fdiv_rn(__fsub_rn(fhmx, fhmn), fhmx);
                float u1 = __fmul_rn(as, au), u2 = __fmul_rn(at, au);
                float c = __fdiv_rn(1.0f, __fadd_rn(__fsqrt_rn(fmaf(u1, u1, 1.0f)),
                                                    __fsqrt_rn(fmaf(u2, u2, 1.0f))));
                ssmin = __fmul_rn(__fmul_rn(fhmn, c), au);
                ssmin = __fadd_rn(ssmin, ssmin);
                ssmax = __fdiv_rn(ga, __fadd_rn(c, c));
            }
        }
    }
}

__device__ inline void f32_slasv2(float f, float g, float h,
                                  float& ssmin, float& ssmax,
                                  float& snr, float& csr, float& snl, float& csl) {
    float ft = f, fa = fabsf(f), ht = h, ha = fabsf(h);
    int pmax = 1;
    bool swp = (ha > fa);
    if (swp) { pmax = 3; float t = ft; ft = ht; ht = t; t = fa; fa = ha; ha = t; }
    float gt = g, ga = fabsf(gt);
    float clt = 0.f, crt = 0.f, slt = 0.f, srt = 0.f;
    if (ga == 0.0f) {
        ssmin = ha; ssmax = fa; clt = 1.0f; crt = 1.0f; slt = 0.0f; srt = 0.0f;
    } else {
        bool gasmal = true;
        if (ga > fa) {
            pmax = 2;
            if (__fdiv_rn(fa, ga) < F32EPS) {
                gasmal = false;
                ssmax = ga;
                if (ha > 1.0f) ssmin = __fdiv_rn(fa, __fdiv_rn(ga, ha));
                else           ssmin = __fmul_rn(__fdiv_rn(fa, ga), ha);
                clt = 1.0f; slt = __fdiv_rn(ht, gt);
                srt = 1.0f; crt = __fdiv_rn(ft, gt);
            }
        }
        if (gasmal) {
            float dd = __fsub_rn(fa, ha);
            float l = (dd == fa) ? 1.0f : __fdiv_rn(dd, fa);
            float vm = __fdiv_rn(gt, ft);
            float t = __fsub_rn(2.0f, l);
            float mm = __fmul_rn(vm, vm);
            float s = __fsqrt_rn(fmaf(t, t, mm));
            float r = (l == 0.0f) ? fabsf(vm) : __fsqrt_rn(fmaf(l, l, mm));
            float a = __fmul_rn(0.5f, __fadd_rn(s, r));
            ssmin = __fdiv_rn(ha, a);
            ssmax = __fmul_rn(fa, a);
            if (mm == 0.0f) {
                if (l == 0.0f) t = __fmul_rn(copysignf(2.0f, ft), copysignf(1.0f, gt));
                else t = __fadd_rn(__fdiv_rn(gt, copysignf(dd, ft)), __fdiv_rn(vm, t));
            } else {
                t = __fmul_rn(__fadd_rn(__fdiv_rn(vm, __fadd_rn(s, t)),
                                        __fdiv_rn(vm, __fadd_rn(r, l))),
                              __fadd_rn(1.0f, a));
            }
            float l2 = __fsqrt_rn(fmaf(t, t, 4.0f));
            crt = __fdiv_rn(2.0f, l2);
            srt = __fdiv_rn(t, l2);
            clt = __fdiv_rn(fmaf(srt, vm, crt), a);
            slt = __fdiv_rn(__fmul_rn(__fdiv_rn(ht, ft), srt), a);
        }
    }
    if (swp) { csl = srt; snl = crt; csr = slt; snr = clt; }
    else     { csl = clt; snl = slt; csr = crt; snr = srt; }
    float tsign = 0.f;
    if (pmax == 1) tsign = __fmul_rn(__fmul_rn(copysignf(1.0f, csr), copysignf(1.0f, csl)), copysignf(1.0f, f));
    if (pmax == 2) tsign = __fmul_rn(__fmul_rn(copysignf(1.0f, snr), copysignf(1.0f, csl)), copysignf(1.0f, g));
    if (pmax == 3) tsign = __fmul_rn(__fmul_rn(copysignf(1.0f, snr), copysignf(1.0f, snl)), copysignf(1.0f, h));
    ssmax = copysignf(ssmax, tsign);
    ssmin = copysignf(ssmin, __fmul_rn(__fmul_rn(tsign, copysignf(1.0f, f)), copysignf(1.0f, h)));
}

__device__ inline void slasr_L(float vt[3][3], int base, int len, const float* c, const float* s, bool fwd) {
    int pairs = len - 1;
    for (int jj = 0; jj < pairs; ++jj) {
        int j = fwd ? jj : (pairs - 1 - jj);
        float cj = c[j], sj = s[j];
        if (cj != 1.0f || sj != 0.0f) {
            for (int i = 0; i < 3; ++i) {
                float temp = vt[base + j + 1][i];
                vt[base + j + 1][i] = fmaf(cj, temp, -__fmul_rn(sj, vt[base + j][i]));
                vt[base + j][i]     = fmaf(sj, temp,  __fmul_rn(cj, vt[base + j][i]));
            }
        }
    }
}
__device__ inline void slasr_R(float u[3][3], int base, int len, const float* c, const float* s, bool fwd) {
    int pairs = len - 1;
    for (int jj = 0; jj < pairs; ++jj) {
        int j = fwd ? jj : (pairs - 1 - jj);
        float cj = c[j], sj = s[j];
        if (cj != 1.0f || sj != 0.0f) {
            for (int i = 0; i < 3; ++i) {
                float temp = u[i][base + j + 1];
                u[i][base + j + 1] = fmaf(cj, temp, -__fmul_rn(sj, u[i][base + j]));
                u[i][base + j]     = fmaf(sj, temp,  __fmul_rn(cj, u[i][base + j]));
            }
        }
    }
}

__device__ void f32_sbdsqr3(float d[3], float e[2], float vt[3][3], float u[3][3]) {
    const int N = 3;
    float TOL = __fmul_rn(10.0f, F32EPS);
    float thresh;
    {
        float sminoa = fabsf(d[0]);
        if (sminoa != 0.0f) {
            float mu = sminoa;
            for (int i = 1; i < N; ++i) {
                mu = __fmul_rn(fabsf(d[i]), __fdiv_rn(mu, __fadd_rn(mu, fabsf(e[i - 1]))));
                sminoa = fminf(sminoa, mu);
                if (sminoa == 0.0f) break;
            }
        }
        sminoa = __fdiv_rn(sminoa, __fsqrt_rn((float)N));
        thresh = fmaxf(__fmul_rn(TOL, sminoa), __fmul_rn(54.0f, F32UNFL));
    }
    int m = N, oldll = -1, oldm = -1, idir = 0;
    int guard = 0;
    while (true) {
        if (m <= 1) break;
        if (++guard > 400) break;
        int ll = 0;
        float smax_blk = fabsf(d[m - 1]);
        bool split = false;
        for (int lll = 1; lll <= m - 1; ++lll) {
            ll = m - lll;
            float abss = fabsf(d[ll - 1]);
            float abse = fabsf(e[ll - 1]);
            if (abse <= thresh) { split = true; break; }
            smax_blk = fmaxf(smax_blk, fmaxf(abss, abse));
        }
        if (split) {
            e[ll - 1] = 0.0f;
            if (ll == m - 1) { m -= 1; continue; }
            ll += 1;
        } else ll = 1;
        if (ll == m - 1) {
            float sigmn, sigmx, sinr, cosr, sinl, cosl;
            f32_slasv2(d[m - 2], e[m - 2], d[m - 1], sigmn, sigmx, sinr, cosr, sinl, cosl);
            d[m - 2] = sigmx; e[m - 2] = 0.0f; d[m - 1] = sigmn;
            for (int i = 0; i < 3; ++i) {
                float x = vt[m - 2][i], y = vt[m - 1][i];
                float temp = fmaf(cosr, x, __fmul_rn(sinr, y));
                vt[m - 1][i] = fmaf(cosr, y, -__fmul_rn(sinr, x));
                vt[m - 2][i] = temp;
            }
            for (int i = 0; i < 3; ++i) {
                float x = u[i][m - 2], y = u[i][m - 1];
                float temp = fmaf(cosl, x, __fmul_rn(sinl, y));
                u[i][m - 1] = fmaf(cosl, y, -__fmul_rn(sinl, x));
                u[i][m - 2] = temp;
            }
            m -= 2;
            continue;
        }
        if (ll > oldm || m < oldll)
            idir = (fabsf(d[ll - 1]) >= fabsf(d[m - 1])) ? 1 : 2;
        float sminl = 0.0f;
        bool deflated = false;
        if (idir == 1) {
            if (fabsf(e[m - 2]) <= __fmul_rn(fabsf(TOL), fabsf(d[m - 1]))) { e[m - 2] = 0.0f; continue; }
            float mu = fabsf(d[ll - 1]);
            sminl = mu;
            for (int lll = ll; lll <= m - 1; ++lll) {
                if (fabsf(e[lll - 1]) <= __fmul_rn(TOL, mu)) { e[lll - 1] = 0.0f; deflated = true; break; }
                mu = __fmul_rn(fabsf(d[lll]), __fdiv_rn(mu, __fadd_rn(mu, fabsf(e[lll - 1]))));
                sminl = fminf(sminl, mu);
            }
        } else {
            if (fabsf(e[ll - 1]) <= __fmul_rn(fabsf(TOL), fabsf(d[ll - 1]))) { e[ll - 1] = 0.0f; continue; }
            float mu = fabsf(d[m - 1]);
            sminl = mu;
            for (int lll = m - 1; lll >= ll; --lll) {
                if (fabsf(e[lll - 1]) <= __fmul_rn(TOL, mu)) { e[lll - 1] = 0.0f; deflated = true; break; }
                mu = __fmul_rn(fabsf(d[lll - 1]), __fdiv_rn(mu, __fadd_rn(mu, fabsf(e[lll - 1]))));
                sminl = fminf(sminl, mu);
            }
        }
        if (deflated) continue;
        oldll = ll; oldm = m;
        float shift = 0.0f, rdum;
        {
            float lhs = __fmul_rn(__fmul_rn((float)N, TOL), __fdiv_rn(sminl, smax_blk));
            float rhs = fmaxf(F32EPS, __fmul_rn(0.01f, TOL));
            if (lhs <= rhs) shift = 0.0f;
            else {
                float sll;
                if (idir == 1) { sll = fabsf(d[ll - 1]); f32_slas2(d[m - 2], e[m - 2], d[m - 1], shift, rdum); }
                else           { sll = fabsf(d[m - 1]);  f32_slas2(d[ll - 1], e[ll - 1], d[ll], shift, rdum); }
                if (sll > 0.0f) {
                    float q = __fdiv_rn(shift, sll);
                    if (__fmul_rn(q, q) < F32EPS) shift = 0.0f;
                }
            }
        }
        float wcs[2], wsn[2], wocs[2], wosn[2];
        int len = m - ll + 1;
        if (shift == 0.0f) {
            if (idir == 1) {
                float cs = 1.0f, oldcs = 1.0f, sn, oldsn = 0.0f, r;
                for (int i = ll; i <= m - 1; ++i) {
                    float fin = __fmul_rn(d[i - 1], cs);
                    f32_slartg(fin, e[i - 1], cs, sn, r);
                    if (i > ll) e[i - 2] = __fmul_rn(oldsn, r);
                    float g = __fmul_rn(d[i], sn);
                    f32_slartg(__fmul_rn(oldcs, r), g, oldcs, oldsn, d[i - 1]);
                    wcs[i - ll] = cs; wsn[i - ll] = sn; wocs[i - ll] = oldcs; wosn[i - ll] = oldsn;
                }
                float h = __fmul_rn(d[m - 1], cs);
                d[m - 1] = __fmul_rn(h, oldcs);
                e[m - 2] = __fmul_rn(h, oldsn);
                slasr_L(vt, ll - 1, len, wcs, wsn, true);
                slasr_R(u, ll - 1, len, wocs, wosn, true);
                if (fabsf(e[m - 2]) <= thresh) e[m - 2] = 0.0f;
            } else {
                float cs = 1.0f, oldcs = 1.0f, sn, oldsn = 0.0f, r;
                for (int i = m; i >= ll + 1; --i) {
                    float fin = __fmul_rn(d[i - 1], cs);
                    f32_slartg(fin, e[i - 2], cs, sn, r);
                    if (i < m) e[i - 1] = __fmul_rn(oldsn, r);
                    float g = __fmul_rn(d[i - 2], sn);
                    f32_slartg(__fmul_rn(oldcs, r), g, oldcs, oldsn, d[i - 1]);
                    wcs[i - ll - 1] = cs; wsn[i - ll - 1] = -sn;
                    wocs[i - ll - 1] = oldcs; wosn[i - ll - 1] = -oldsn;
                }
                float h = __fmul_rn(d[ll - 1], cs);
                d[ll - 1] = __fmul_rn(h, oldcs);
                e[ll - 1] = __fmul_rn(h, oldsn);
                slasr_L(vt, ll - 1, len, wocs, wosn, false);
                slasr_R(u, ll - 1, len, wcs, wsn, false);
                if (fabsf(e[ll - 1]) <= thresh) e[ll - 1] = 0.0f;
            }
        } else {
            if (idir == 1) {
                float f = __fmul_rn(__fsub_rn(fabsf(d[ll - 1]), shift),
                                    __fadd_rn(copysignf(1.0f, d[ll - 1]), __fdiv_rn(shift, d[ll - 1])));
                float g = e[ll - 1];
                float cosr, sinr, cosl, sinl, r;
                for (int i = ll; i <= m - 1; ++i) {
                    f32_slartg(f, g, cosr, sinr, r);
                    if (i > ll) e[i - 2] = r;
                    f        = fmaf(cosr, d[i - 1],  __fmul_rn(sinr, e[i - 1]));
                    e[i - 1] = fmaf(cosr, e[i - 1], -__fmul_rn(sinr, d[i - 1]));
                    g = __fmul_rn(sinr, d[i]);
                    d[i] = __fmul_rn(cosr, d[i]);
                    f32_slartg(f, g, cosl, sinl, r);
                    d[i - 1] = r;
                    f    = fmaf(cosl, e[i - 1],  __fmul_rn(sinl, d[i]));
                    d[i] = fmaf(cosl, d[i],     -__fmul_rn(sinl, e[i - 1]));
                    if (i < m - 1) {
                        g = __fmul_rn(sinl, e[i]);
                        e[i] = __fmul_rn(cosl, e[i]);
                    }
                    wcs[i - ll] = cosr; wsn[i - ll] = sinr; wocs[i - ll] = cosl; wosn[i - ll] = sinl;
                }
                e[m - 2] = f;
                if (fabsf(e[m - 2]) <= thresh) e[m - 2] = 0.0f;
                slasr_L(vt, ll - 1, len, wcs, wsn, true);
                slasr_R(u, ll - 1, len, wocs, wosn, true);
            } else {
                float f = __fmul_rn(__fsub_rn(fabsf(d[m - 1]), shift),
                                    __fadd_rn(copysignf(1.0f, d[m - 1]), __fdiv_rn(shift, d[m - 1])));
                float g = e[m - 2];
                float cosr, sinr, cosl, sinl, r;
                for (int i = m; i >= ll + 1; --i) {
                    f32_slartg(f, g, cosr, sinr, r);
                    if (i < m) e[i - 1] = r;
                    f        = fmaf(cosr, d[i - 1],  __fmul_rn(sinr, e[i - 2]));
                    e[i - 2] = fmaf(cosr, e[i - 2], -__fmul_rn(sinr, d[i - 1]));
                    g = __fmul_rn(sinr, d[i - 2]);
                    d[i - 2] = __fmul_rn(cosr, d[i - 2]);
                    f32_slartg(f, g, cosl, sinl, r);
                    d[i - 1] = r;
                    f        = fmaf(cosl, e[i - 2],  __fmul_rn(sinl, d[i - 2]));
                    d[i - 2] = fmaf(cosl, d[i - 2], -__fmul_rn(sinl, e[i - 2]));
                    if (i > ll + 1) {
                        g = __fmul_rn(sinl, e[i - 3]);
                        e[i - 3] = __fmul_rn(cosl, e[i - 3]);
                    }
                    wcs[i - ll - 1] = cosr; wsn[i - ll - 1] = -sinr;
                    wocs[i - ll - 1] = cosl; wosn[i - ll - 1] = -sinl;
                }
                e[ll - 1] = f;
                if (fabsf(e[ll - 1]) <= thresh) e[ll - 1] = 0.0f;
                slasr_L(vt, ll - 1, len, wocs, wosn, false);
                slasr_R(u, ll - 1, len, wcs, wsn, false);
            }
        }
    }
    for (int i = 0; i < N; ++i) {
        if (d[i] < 0.0f) {
            d[i] = -d[i];
            for (int j = 0; j < 3; ++j) vt[i][j] = __fmul_rn(-1.0f, vt[i][j]);
        }
    }
    for (int i = 1; i <= N - 1; ++i) {
        int isub = 0; float smin = d[0];
        for (int j = 1; j <= N - i; ++j)
            if (d[j] <= smin) { isub = j; smin = d[j]; }
        int tgt = N - i;
        if (isub != tgt) {
            d[isub] = d[tgt]; d[tgt] = smin;
            for (int j = 0; j < 3; ++j) { float t = vt[isub][j]; vt[isub][j] = vt[tgt][j]; vt[tgt][j] = t; }
            for (int j = 0; j < 3; ++j) { float t = u[j][isub]; u[j][isub] = u[j][tgt]; u[j][tgt] = t; }
        }
    }
}

__device__ void sgesdd3_rot(float a[3][3], float rot[3][3]) {
    float d[3], e[2], tauq2, tauq1, taup1;
    {
        float x[2] = { a[1][0], a[2][0] };
        float alpha = a[0][0];
        tauq1 = f32_slarfg(2, alpha, x);
        a[1][0] = x[0]; a[2][0] = x[1];
        d[0] = alpha;
        if (tauq1 != 0.0f) {
            float v1 = a[1][0], v2 = a[2][0];
            for (int j = 1; j < 3; ++j) {
                float w = a[0][j];
                w = fmaf(a[1][j], v1, w);
                w = fmaf(a[2][j], v2, w);
                float tmp = __fmul_rn(-tauq1, w);
                a[0][j] = __fadd_rn(a[0][j], tmp);
                a[1][j] = fmaf(v1, tmp, a[1][j]);
                a[2][j] = fmaf(v2, tmp, a[2][j]);
            }
        }
    }
    {
        float x[1] = { a[0][2] };
        float alpha = a[0][1];
        taup1 = f32_slarfg(1, alpha, x);
        a[0][2] = x[0];
        e[0] = alpha; a[0][1] = alpha;
        if (taup1 != 0.0f) {
            float v1 = a[0][2];
            float w1 = fmaf(a[1][2], v1, a[1][1]);
            float w2 = fmaf(a[2][2], v1, a[2][1]);
            float nt = -taup1;
            float t0 = __fmul_rn(nt, 1.0f);
            a[1][1] = fmaf(w1, t0, a[1][1]);
            a[2][1] = fmaf(w2, t0, a[2][1]);
            float t1 = __fmul_rn(nt, v1);
            a[1][2] = fmaf(w1, t1, a[1][2]);
            a[2][2] = fmaf(w2, t1, a[2][2]);
        }
    }
    {
        float x[1] = { a[2][1] };
        float alpha = a[1][1];
        tauq2 = f32_slarfg(1, alpha, x);
        a[2][1] = x[0];
        d[1] = alpha;
        if (tauq2 != 0.0f) {
            float v1 = a[2][1];
            float w = a[1][2];
            w = fmaf(a[2][2], v1, w);
            float tmp = __fmul_rn(-tauq2, w);
            a[1][2] = __fadd_rn(a[1][2], tmp);
            a[2][2] = fmaf(v1, tmp, a[2][2]);
        }
        e[1] = a[1][2];
    }
    d[2] = a[2][2];
    float u[3][3], vt[3][3];
    for (int i = 0; i < 3; ++i)
        for (int j = 0; j < 3; ++j) { u[i][j] = (i == j) ? 1.0f : 0.0f; vt[i][j] = (i == j) ? 1.0f : 0.0f; }
    f32_sbdsqr3(d, e, vt, u);
    if (tauq2 != 0.0f) {
        float v1 = a[2][1];
        for (int j = 0; j < 3; ++j) {
            float w = u[1][j];
            w = fmaf(u[2][j], v1, w);
            float tmp = __fmul_rn(-tauq2, w);
            u[1][j] = __fadd_rn(u[1][j], tmp);
            u[2][j] = fmaf(v1, tmp, u[2][j]);
        }
    }
    if (tauq1 != 0.0f) {
        float v1 = a[1][0], v2 = a[2][0];
        for (int j = 0; j < 3; ++j) {
            float w = u[0][j];
            w = fmaf(u[1][j], v1, w);
            w = fmaf(u[2][j], v2, w);
            float tmp = __fmul_rn(-tauq1, w);
            u[0][j] = __fadd_rn(u[0][j], tmp);
            u[1][j] = fmaf(v1, tmp, u[1][j]);
            u[2][j] = fmaf(v2, tmp, u[2][j]);
        }
    }
    if (taup1 != 0.0f) {
        float v1 = a[0][2];
        float w0 = fmaf(vt[0][2], v1, vt[0][1]);
        float w1 = fmaf(vt[1][2], v1, vt[1][1]);
        float w2 = fmaf(vt[2][2], v1, vt[2][1]);
        float nt = -taup1;
        float t0 = __fmul_rn(nt, 1.0f);
        vt[0][1] = fmaf(w0, t0, vt[0][1]);
        vt[1][1] = fmaf(w1, t0, vt[1][1]);
        vt[2][1] = fmaf(w2, t0, vt[2][1]);
        float t1 = __fmul_rn(nt, v1);
        vt[0][2] = fmaf(w0, t1, vt[0][2]);
        vt[1][2] = fmaf(w1, t1, vt[1][2]);
        vt[2][2] = fmaf(w2, t1, vt[2][2]);
    }
    for (int i = 0; i < 3; ++i)
        for (int j = 0; j < 3; ++j) {
            float acc = __fmul_rn(vt[0][i], u[j][0]);
            acc = __fadd_rn(acc, __fmul_rn(vt[1][i], u[j][1]));
            acc = __fadd_rn(acc, __fmul_rn(vt[2][i], u[j][2]));
            rot[i][j] = acc;
        }
}

// ================= kernels =================

// grid = inst*4 (quarter blocks); block 384 = 6 waves (wave=channel).
__global__ __launch_bounds__(384)
void cog_kernel(const float* __restrict__ A, const float* __restrict__ Ag,
                const float* __restrict__ Bc, const float* __restrict__ Bg,
                int Bn, long long N, float* __restrict__ cogs /*[inst][6][4]*/)
{
    int inst = blockIdx.x >> 2;
    int qt = blockIdx.x & 3;
    int pair = inst / Bn, b = inst % Bn;
    const float* P = (pair ? Bc : A)  + (long long)b * 3 * N;
    const float* Q = (pair ? Bg : Ag) + (long long)b * 3 * N;
    int ch = threadIdx.x >> 6, lane = threadIdx.x & 63;
    RawF f;
    f.a = (ch < 3) ? (P + (long long)ch * N) : (Q + (long long)(ch - 3) * N);
    int node = qt * 64 + lane;
    int off = 0, n = (int)N;
#pragma unroll
    for (int lvl = 7; lvl >= 0; --lvl) {
        int n2 = (n / 2) & ~7;
        if ((node >> lvl) & 1) { off += n2; n -= n2; } else n = n2;
    }
    float s = tree_raw(f, off, n);
#pragma unroll
    for (int lvl = 0; lvl < 6; ++lvl)
        s = __fadd_rn(s, __shfl_down(s, 1 << lvl, 64));
    if (lane == 0) cogs[(inst * 6 + ch) * 4 + qt] = s;
}

__global__ __launch_bounds__(64)
void hypoT_kernel(const float* __restrict__ A, const float* __restrict__ Ag,
                  const float* __restrict__ Bc, const float* __restrict__ Bg,
                  const int* __restrict__ idxA, const int* __restrict__ idxB,
                  const float* __restrict__ cogs, int Bn, long long N,
                  float* __restrict__ Tall)
{
    int inst = blockIdx.x;
    int pair = inst / Bn, b = inst % Bn;
    const float* P = (pair ? Bc : A)  + (long long)b * 3 * N;
    const float* Q = (pair ? Bg : Ag) + (long long)b * 3 * N;
    const int* idx = pair ? idxB : idxA;

    int m = threadIdx.x;
    if (m >= M_HYP) return;

    float S[6];
#pragma unroll
    for (int ch = 0; ch < 6; ++ch) {
        const float* g = cogs + (inst * 6 + ch) * 4;
        S[ch] = __fadd_rn(__fadd_rn(g[0], g[1]), __fadd_rn(g[2], g[3]));
    }

    float x[12], y[12];
#pragma unroll
    for (int j = 0; j < 12; ++j) {
        int f = m * 12 + j, c = f / 80, i = f % 80;
        int id = idx[i];
        x[j] = __fsub_rn(P[(long long)c * N + id], S[c]);
        y[j] = __fsub_rn(Q[(long long)c * N + id], S[3 + c]);
    }
    float cov[3][3];
#pragma unroll
    for (int r = 0; r < 3; ++r)
#pragma unroll
        for (int dcol = 0; dcol < 3; ++dcol) {
            float s = __fmul_rn(x[r * 4 + 0], y[dcol * 4 + 0]);
            s = __fadd_rn(s, __fmul_rn(x[r * 4 + 1], y[dcol * 4 + 1]));
            s = __fadd_rn(s, __fmul_rn(x[r * 4 + 2], y[dcol * 4 + 2]));
            s = __fadd_rn(s, __fmul_rn(x[r * 4 + 3], y[dcol * 4 + 3]));
            cov[r][dcol] = s;
        }

    float rot[3][3];
    sgesdd3_rot(cov, rot);

    float* T = Tall + ((long long)inst * M_HYP + m) * 12;
#pragma unroll
    for (int r = 0; r < 3; ++r) {
        T[r * 4 + 0] = rot[r][0];
        T[r * 4 + 1] = rot[r][1];
        T[r * 4 + 2] = rot[r][2];
        T[r * 4 + 3] = __fsub_rn(S[3 + r], S[r]);
    }
}

// grid = inst*128 (depth-7 tree nodes), SINGLE-wave blocks (round-8 code
// per wave, compile-time LDS base). 64 lanes = 60 (m,c) combos walking the
// node in lockstep (broadcast LDS reads). 32 blocks/CU -> LDS-capped ~24.
__global__ __launch_bounds__(64)
void err_partial(const float* __restrict__ A, const float* __restrict__ Ag,
                 const float* __restrict__ Bc, const float* __restrict__ Bg,
                 const float* __restrict__ Tall, int Bn, long long N,
                 float* __restrict__ partials /*[inst][20][3][128]*/)
{
    int inst = blockIdx.x >> 7;
    int node = blockIdx.x & 127;
    int pair = inst / Bn, b = inst % Bn;
    const float* P = (pair ? Bc : A)  + (long long)b * 3 * N;
    const float* Q = (pair ? Bg : Ag) + (long long)b * 3 * N;

    int lane = threadIdx.x;
    int combo = lane < 60 ? lane : 59;
    int m = combo / 3, c = combo - m * 3;
    const float* T = Tall + ((long long)inst * M_HYP + m) * 12;

    __shared__ float sm[6][264];

    int off = 0, n = (int)N;
#pragma unroll
    for (int lvl = 6; lvl >= 0; --lvl) {
        int n2 = (n / 2) & ~7;
        if ((node >> lvl) & 1) { off += n2; n -= n2; } else n = n2;
    }

    Stg st;
    st.g0 = P; st.g1 = P + N; st.g2 = P + 2 * N;
    st.g3 = Q; st.g4 = Q + N; st.g5 = Q + 2 * N;
    st.sm = sm;
    st.node_end = off + n;
    st.lane = lane;
    st.qs = 3 + c;
    st.t0 = T[c * 4 + 0]; st.t1 = T[c * 4 + 1];
    st.t2 = T[c * 4 + 2]; st.t3 = T[c * 4 + 3];
    st.tile_base = off;
    stage6(st, off);

    float s = tree_err(st, off, n);
    if (lane < 60)
        partials[(((long long)inst * M_HYP + m) * 3 + c) * 128 + node] = s;
}

// grid = Bn; combines the 128 node partials in exact tree order (pairwise
// first level folded during load), sqrt, argmin, fp64 inverse + compose.
__global__ __launch_bounds__(64)
void final_kernel(const float* __restrict__ partials, const float* __restrict__ Tall,
                  int Bn, float* __restrict__ out)
{
    int b = blockIdx.x;
    __shared__ float errsh[2][M_HYP];
    int t = threadIdx.x;
    if (t < 2 * M_HYP) {
        int pair = t / M_HYP, m = t % M_HYP;
        int inst = pair * Bn + b;
        float S[3];
#pragma unroll
        for (int c = 0; c < 3; ++c) {
            const float* g = partials + (((long long)inst * M_HYP + m) * 3 + c) * 128;
            float v[64];
#pragma unroll
            for (int i = 0; i < 64; ++i) v[i] = __fadd_rn(g[2 * i], g[2 * i + 1]);
#pragma unroll
            for (int lvl = 0; lvl < 6; ++lvl) {
#pragma unroll
                for (int i = 0; i < 32; ++i)
                    if (i < (32 >> lvl)) v[i] = __fadd_rn(v[2 * i], v[2 * i + 1]);
            }
            S[c] = v[0];
        }
        errsh[pair][m] = __fsqrt_rn(__fadd_rn(__fadd_rn(S[0], S[1]), S[2]));
    }
    __syncthreads();
    if (t == 0) {
        int bm[2];
#pragma unroll
        for (int pair = 0; pair < 2; ++pair) {
            int bi = 0; float be = errsh[pair][0];
            for (int mm = 1; mm < M_HYP; ++mm)
                if (errsh[pair][mm] < be) { be = errsh[pair][mm]; bi = mm; }
            bm[pair] = bi;
        }
        float TA[16], TB[16];
        const float* TsA = Tall + ((long long)(0 * Bn + b) * M_HYP + bm[0]) * 12;
        const float* TsB = Tall + ((long long)(1 * Bn + b) * M_HYP + bm[1]) * 12;
        for (int j = 0; j < 12; ++j) { TA[j] = TsA[j]; TB[j] = TsB[j]; }
        TA[12] = TA[13] = TA[14] = 0.0f; TA[15] = 1.0f;
        TB[12] = TB[13] = TB[14] = 0.0f; TB[15] = 1.0f;

        double M[4][8];
        for (int i = 0; i < 4; ++i) {
            for (int j = 0; j < 4; ++j) { M[i][j] = (double)TA[i * 4 + j]; M[i][4 + j] = 0.0; }
            M[i][4 + i] = 1.0;
        }
        for (int cc = 0; cc < 4; ++cc) {
            int piv = cc; double mx = fabs(M[cc][cc]);
            for (int r = cc + 1; r < 4; ++r) { double v = fabs(M[r][cc]); if (v > mx) { mx = v; piv = r; } }
            if (piv != cc)
                for (int j = 0; j < 8; ++j) { double tt = M[cc][j]; M[cc][j] = M[piv][j]; M[piv][j] = tt; }
            double dd = 1.0 / M[cc][cc];
            for (int j = 0; j < 8; ++j) M[cc][j] *= dd;
            for (int r = 0; r < 4; ++r) {
                if (r == cc) continue;
                double ff = M[r][cc];
                for (int j = 0; j < 8; ++j) M[r][j] -= ff * M[cc][j];
            }
        }
        for (int i = 0; i < 4; ++i)
            for (int j = 0; j < 4; ++j) {
                double s = 0.0;
                for (int k = 0; k < 4; ++k) s += M[i][4 + k] * (double)TB[k * 4 + j];
                out[b * 16 + i * 4 + j] = (float)s;
            }
    }
}

extern "C" void kernel_launch(void* const* d_in, const int* in_sizes, int n_in,
                              void* d_out, int out_size, void* d_ws, size_t ws_size,
                              hipStream_t stream) {
    const float* A    = (const float*)d_in[0];
    const float* Ag   = (const float*)d_in[1];
    const float* Bc   = (const float*)d_in[2];
    const float* Bg   = (const float*)d_in[3];
    const int*   idxA = (const int*)d_in[4];
    const int*   idxB = (const int*)d_in[5];
    float* out = (float*)d_out;

    int Bn = out_size / 16;                              // 32
    long long N = (long long)in_sizes[0] / (3LL * Bn);   // 100000
    int inst = 2 * Bn;                                   // 64

    float* cogs     = (float*)d_ws;                              // inst*6*4
    float* Tall     = cogs + (size_t)inst * 6 * 4;               // inst*M_HYP*12
    float* partials = Tall + (size_t)inst * M_HYP * 12;          // inst*M_HYP*3*128

    cog_kernel  <<<inst * 4,   384, 0, stream>>>(A, Ag, Bc, Bg, Bn, N, cogs);
    hypoT_kernel<<<inst,        64, 0, stream>>>(A, Ag, Bc, Bg, idxA, idxB, cogs, Bn, N, Tall);
    err_partial <<<inst * 128,  64, 0, stream>>>(A, Ag, Bc, Bg, Tall, Bn, N, partials);
    final_kernel<<<Bn,          64, 0, stream>>>(partials, Tall, Bn, out);
}